// Round 9
// baseline (377.484 us; speedup 1.0000x reference)
//
#include <hip/hip_runtime.h>
#include <hip/hip_bf16.h>
#include <math.h>

#define NN 50000
#define NE 500000
#define DD 128
#define STR 136   // LDS activation row stride in bf16 elements
#define NSCAN (2 * NN)
#define SCAN_BLK ((NSCAN + 1023) / 1024)          // 98
#define HIST_BLK ((NE + 255) / 256)               // 1954
#define CVT_BLK  ((NN * DD + 4095) / 4096)        // 1563
#define PRECONV_BLK ((7 * 2048 + 1023) / 1024)    // 14
#define ENC_BLK  ((NN + 127) / 128)               // 391
#define AGG_BLK  ((NN + 3) / 4)                   // 12500
#define NODE_BLK ((NN + 63) / 64)                 // 782

typedef __attribute__((ext_vector_type(8))) short short8;
typedef __attribute__((ext_vector_type(4))) float floatx4;

__device__ __forceinline__ float bf2f(unsigned short u) {
    unsigned v = ((unsigned)u) << 16;
    float f;
    __builtin_memcpy(&f, &v, 4);
    return f;
}
__device__ __forceinline__ unsigned short f2bf(float f) {
    unsigned x;
    __builtin_memcpy(&x, &f, 4);
    x += 0x7FFF + ((x >> 16) & 1);   // RNE
    return (unsigned short)(x >> 16);
}
// tanh(x) = 1 - 2/(e^{2x}+1). Branch-free, 2 transcendentals.
__device__ __forceinline__ float fast_tanh(float x) {
    float t = __builtin_amdgcn_exp2f(x * 2.88539008177793f);
    return 1.f - 2.f * __builtin_amdgcn_rcpf(t + 1.f);
}

// ---------------------------------------------------------------------------
// K1: three independent jobs in one dispatch.
//  blocks [0,1954):         hist (dual counting-sort histograms + ranks)
//  blocks [1954,1954+1563): x (f32) -> xbf (bf16), coalesced
//  blocks [3517,3517+7):    composite weights + bias vectors
// ---------------------------------------------------------------------------
__global__ __launch_bounds__(256) void k1_kernel(
    const int* __restrict__ src, const int* __restrict__ dst,
    int* __restrict__ cnt_dst, int* __restrict__ cnt_src,
    int* __restrict__ rank_d, int* __restrict__ rank_s,
    const float* __restrict__ x, unsigned short* __restrict__ xbf,
    const float* __restrict__ U0W, const float* __restrict__ WencP1,
    const float* __restrict__ WencP2, const float* __restrict__ K0W,
    const float* __restrict__ WencK,
    const float* __restrict__ bp1, const float* __restrict__ bp2,
    const float* __restrict__ U0b, const float* __restrict__ bk,
    const float* __restrict__ U2b,
    float* __restrict__ comp, float* __restrict__ bvecs)
{
    __shared__ float Bs[DD * DD];
    int blk = blockIdx.x;
    int t = threadIdx.x;

    if (blk < HIST_BLK) {
        int e = blk * 256 + t;
        if (e < NE) {
            rank_d[e] = atomicAdd(&cnt_dst[dst[e]], 1);
            rank_s[e] = atomicAdd(&cnt_src[src[e]], 1);
        }
        return;
    }
    if (blk < HIST_BLK + CVT_BLK) {
        int base = (blk - HIST_BLK) * 4096;
        #pragma unroll
        for (int j = 0; j < 4; ++j) {
            int idx = base + (j * 256 + t) * 4;
            if (idx < NN * DD) {
                float4 f = *(const float4*)&x[idx];
                ushort4 v4;
                v4.x = f2bf(f.x); v4.y = f2bf(f.y);
                v4.z = f2bf(f.z); v4.w = f2bf(f.w);
                *(ushort4*)&xbf[idx] = v4;
            }
        }
        return;
    }

    int b = blk - (HIST_BLK + CVT_BLK);   // 0..6
    if (b == 6) {
        if (t < 128) {
            float s1 = 0.f, s2 = 0.f;
            for (int k = 0; k < DD; ++k) {
                s1 += U0W[t * DD + k] * (bp1[k] + bp2[k]);
                s2 += K0W[t * DD + k] * bk[k];
            }
            bvecs[t] = s1 + U0b[t];
            bvecs[128 + t] = s2;
            int f = (t & 64) + 16 * (t & 3) + ((t & 63) >> 2);
            bvecs[256 + t] = U2b[f];
        }
        return;
    }
    int mat = b >> 1, half = b & 1;
    const float* A = (mat == 2) ? K0W : U0W;
    const float* B = (mat == 0) ? WencP1 : (mat == 1) ? WencP2 : WencK;
    float* C = comp + (size_t)mat * DD * DD;
    for (int i = 0; i < 64; ++i)
        Bs[i * 256 + t] = B[i * 256 + t];
    __syncthreads();
    int row = half * 64 + (t >> 2);
    int j0 = (t & 3) * 32;
    float acc[32];
    #pragma unroll
    for (int jj = 0; jj < 32; ++jj) acc[jj] = 0.f;
    for (int k = 0; k < DD; ++k) {
        float a = A[row * DD + k];
        #pragma unroll
        for (int jj = 0; jj < 32; ++jj)
            acc[jj] += a * Bs[k * DD + j0 + jj];
    }
    #pragma unroll
    for (int jj = 0; jj < 32; ++jj) C[row * DD + j0 + jj] = acc[jj];
}

// ---------------------------------------------------------------------------
// K2: preconv (frag conversion) blocks [0,14) + scan1 blocks [14,112).
// Frags: 0=Wq1(nat) 1=Wq2(nat) 2=WkK0(nat) 3=K1W(perm) 4=K2W(perm)
//        5=U2W(perm+transpose) 6=U1W(nat)
// scan1 leaves block-LOCAL exclusive prefixes in base; bsum gets block sums.
// ---------------------------------------------------------------------------
__global__ __launch_bounds__(1024) void k2_kernel(
    const float* __restrict__ comp, const float* __restrict__ K1W,
    const float* __restrict__ K2W, const float* __restrict__ U2W,
    const float* __restrict__ U1W, unsigned short* __restrict__ wfrag,
    const int* __restrict__ cnt, int* __restrict__ base, int* __restrict__ bsum)
{
    int t = threadIdx.x;
    if (blockIdx.x < PRECONV_BLK) {
        int g = blockIdx.x * 1024 + t;
        if (g >= 7 * 2048) return;
        int m = g >> 11;
        int rem = g & 2047;
        int kt = rem >> 9, nt = (rem >> 6) & 7, lane = rem & 63;
        const float* W;
        bool perm = false, tr = false;
        switch (m) {
            case 0: W = comp; break;
            case 1: W = comp + 16384; break;
            case 2: W = comp + 32768; break;
            case 3: W = K1W; perm = true; break;
            case 4: W = K2W; perm = true; break;
            case 5: W = U2W; perm = true; tr = true; break;
            default: W = U1W; break;
        }
        int n = nt * 16 + (lane & 15);
        #pragma unroll
        for (int j = 0; j < 8; ++j) {
            int ks = kt * 32 + (lane >> 4) * 8 + j;
            int f = perm ? (ks & 64) + 16 * (ks & 3) + ((ks & 63) >> 2) : ks;
            float v = tr ? W[f * DD + n] : W[n * DD + f];
            wfrag[(size_t)g * 8 + j] = f2bf(v);
        }
        return;
    }
    // scan1 over concatenated [cnt_dst | cnt_src]
    __shared__ int wsum[16];
    int sb = blockIdx.x - PRECONV_BLK;
    int i = sb * 1024 + t;
    int v = (i < NSCAN) ? cnt[i] : 0;
    int lane = t & 63, w = t >> 6;
    int xv = v;
    #pragma unroll
    for (int off = 1; off < 64; off <<= 1) {
        int y = __shfl_up(xv, off);
        if (lane >= off) xv += y;
    }
    if (lane == 63) wsum[w] = xv;
    __syncthreads();
    if (w == 0) {
        int s = (lane < 16) ? wsum[lane] : 0;
        #pragma unroll
        for (int off = 1; off < 16; off <<= 1) {
            int y = __shfl_up(s, off);
            if (lane >= off) s += y;
        }
        if (lane < 16) wsum[lane] = s;
    }
    __syncthreads();
    int wavebase = (w == 0) ? 0 : wsum[w - 1];
    int incl = wavebase + xv;
    if (i < NSCAN) base[i] = incl - v;
    if (t == 1023) bsum[sb] = incl;
}

__global__ __launch_bounds__(128) void scan2_kernel(
    int* __restrict__ bsum, float* __restrict__ out)
{
    if (threadIdx.x == 0 && blockIdx.x == 0) *out = 0.f;  // zero d_out here
    __shared__ int wsum[2];
    int t = threadIdx.x;
    int v = (t < SCAN_BLK) ? bsum[t] : 0;
    int lane = t & 63, w = t >> 6;
    int x = v;
    #pragma unroll
    for (int off = 1; off < 64; off <<= 1) {
        int y = __shfl_up(x, off);
        if (lane >= off) x += y;
    }
    if (lane == 63) wsum[w] = x;
    __syncthreads();
    int wavebase = (w == 0) ? 0 : wsum[0];
    int incl = wavebase + x;
    if (t < SCAN_BLK) bsum[t] = incl - v;
}

// ---------------------------------------------------------------------------
// place: global offset = base[i] (block-local) + bsum[i>>10] (block offset).
// by-src output packed as int2 (sid, dst) -> one 8B scatter.
// ---------------------------------------------------------------------------
__global__ __launch_bounds__(256) void place_kernel(
    const int* __restrict__ src, const int* __restrict__ dst,
    const int* __restrict__ base, const int* __restrict__ bsum,
    const int* __restrict__ rank_d, const int* __restrict__ rank_s,
    int* __restrict__ sorted_src_bydst, int2* __restrict__ epairs)
{
    int e = blockIdx.x * 256 + threadIdx.x;
    if (e < NE) {
        int s = src[e], d = dst[e];
        sorted_src_bydst[base[d] + bsum[d >> 10] + rank_d[e]] = s;
        int si = NN + s;
        int p = base[si] + bsum[si >> 10] + rank_s[e] - NE;
        epairs[p] = make_int2(s, d);
    }
}

// ---------------------------------------------------------------------------
// aggenc: blocks [0,391) = enc (q1,q2 from x, MFMA-bound);
//         blocks [391,391+12500) = agg (gather-latency-bound).
// Co-scheduled so agg's memory stalls hide enc's compute.
// ---------------------------------------------------------------------------
__global__ __launch_bounds__(256) void aggenc_kernel(
    const float* __restrict__ x, const unsigned short* __restrict__ xbf,
    const unsigned short* __restrict__ wf, const float* __restrict__ bvecs,
    const int* __restrict__ base, const int* __restrict__ bsum,
    const int* __restrict__ cnt, const int* __restrict__ sorted_src,
    unsigned short* __restrict__ q1, unsigned short* __restrict__ q2,
    unsigned short* __restrict__ xagg)
{
    __shared__ unsigned short A[128 * STR];
    const int t = threadIdx.x;
    const int lane = t & 63, w = t >> 6;

    if (blockIdx.x >= ENC_BLK) {
        // ---------------- agg: one wave per node ----------------
        int node = (blockIdx.x - ENC_BLK) * 4 + w;
        if (node >= NN) return;
        int lo = base[node] + bsum[node >> 10];
        int hi = lo + cnt[node];
        float ax = 0.f, ay = 0.f;
        for (int off = lo; off < hi; off += 64) {
            int myid = (off + lane < hi) ? sorted_src[off + lane] : 0;
            int nk = min(64, hi - off);
            int k = 0;
            for (; k + 4 <= nk; k += 4) {
                int s0 = __shfl(myid, k);
                int s1 = __shfl(myid, k + 1);
                int s2 = __shfl(myid, k + 2);
                int s3 = __shfl(myid, k + 3);
                ushort2 v0 = *(const ushort2*)&xbf[(size_t)s0 * DD + lane * 2];
                ushort2 v1 = *(const ushort2*)&xbf[(size_t)s1 * DD + lane * 2];
                ushort2 v2 = *(const ushort2*)&xbf[(size_t)s2 * DD + lane * 2];
                ushort2 v3 = *(const ushort2*)&xbf[(size_t)s3 * DD + lane * 2];
                ax += bf2f(v0.x) + bf2f(v1.x) + bf2f(v2.x) + bf2f(v3.x);
                ay += bf2f(v0.y) + bf2f(v1.y) + bf2f(v2.y) + bf2f(v3.y);
            }
            for (; k < nk; ++k) {
                int s = __shfl(myid, k);
                ushort2 v = *(const ushort2*)&xbf[(size_t)s * DD + lane * 2];
                ax += bf2f(v.x);
                ay += bf2f(v.y);
            }
        }
        ushort2 o;
        o.x = f2bf(ax); o.y = f2bf(ay);
        *(ushort2*)&xagg[(size_t)node * DD + lane * 2] = o;
        return;
    }

    // ---------------- enc ----------------
    const int wm = w >> 1, wn = w & 1;
    const int c = lane & 15, q = lane >> 4;
    const int row0 = blockIdx.x * 128;
    #pragma unroll
    for (int i = 0; i < 16; ++i) {
        int idx = i * 256 + t;
        int r = idx >> 5, ch = idx & 31;
        int gr = row0 + r;
        ushort4 v4 = {0, 0, 0, 0};
        if (gr < NN) {
            float4 f = *(const float4*)&x[(size_t)gr * DD + ch * 4];
            v4.x = f2bf(f.x); v4.y = f2bf(f.y);
            v4.z = f2bf(f.z); v4.w = f2bf(f.w);
        }
        *(ushort4*)&A[r * STR + ch * 4] = v4;
    }
    __syncthreads();

    for (int l = 0; l < 2; ++l) {
        floatx4 acc[4][4];
        #pragma unroll
        for (int i = 0; i < 4; ++i)
            #pragma unroll
            for (int j = 0; j < 4; ++j)
                acc[i][j] = (floatx4){0.f, 0.f, 0.f, 0.f};
        const short8* W8 = (const short8*)(wf + (size_t)l * 16384);
        #pragma unroll
        for (int kt = 0; kt < 4; ++kt) {
            short8 af[4], bfr[4];
            #pragma unroll
            for (int i = 0; i < 4; ++i)
                af[i] = *(const short8*)&A[(wm * 64 + i * 16 + c) * STR + kt * 32 + q * 8];
            #pragma unroll
            for (int j = 0; j < 4; ++j)
                bfr[j] = W8[(kt * 8 + wn * 4 + j) * 64 + lane];
            #pragma unroll
            for (int i = 0; i < 4; ++i)
                #pragma unroll
                for (int j = 0; j < 4; ++j)
                    acc[i][j] = __builtin_amdgcn_mfma_f32_16x16x32_bf16(af[i], bfr[j], acc[i][j], 0, 0, 0);
        }
        unsigned short* pp = (l == 0) ? q1 : q2;
        float bv[4];
        #pragma unroll
        for (int j = 0; j < 4; ++j)
            bv[j] = (l == 0) ? bvecs[c + 16 * j + 64 * wn] : 0.f;

        #pragma unroll
        for (int i = 0; i < 4; ++i)
            #pragma unroll
            for (int r = 0; r < 4; ++r) {
                int node = row0 + wm * 64 + i * 16 + 4 * q + r;
                if (node < NN) {
                    #pragma unroll
                    for (int j = 0; j < 4; ++j)
                        pp[(size_t)node * DD + c + 16 * j + 64 * wn] = f2bf(acc[i][j][r] + bv[j]);
                }
            }
    }
}

// ---------------------------------------------------------------------------
// node: 64-row tiles, 2 waves (wn = wave id), 782 blocks for full fill.
//  L0: WkK0, bias K0b + cnt*bvec, tanh -> LDS (pi)  L1: K1W, relu -> LDS (pi)
//  L2: K2W -> Kn LDS (pi); kb = Kn.U2b             L3: U2^T -> Km global (pi)
// ---------------------------------------------------------------------------
__global__ __launch_bounds__(128) void node_kernel(
    const unsigned short* __restrict__ xagg, const unsigned short* __restrict__ wf,
    const int* __restrict__ cnt, const float* __restrict__ bvecs,
    const float* __restrict__ K0b, const float* __restrict__ K1b,
    const float* __restrict__ K2b,
    unsigned short* __restrict__ Km, float* __restrict__ kb)
{
    __shared__ unsigned short A[64 * STR];
    const int t = threadIdx.x;
    const int lane = t & 63, wn = t >> 6;
    const int c = lane & 15, q = lane >> 4;
    const int row0 = blockIdx.x * 64;

    #pragma unroll
    for (int i = 0; i < 8; ++i) {
        int idx = i * 128 + t;
        int r = idx >> 4, ch = idx & 15;
        int gr = row0 + r;
        short8 v = (short8){0,0,0,0,0,0,0,0};
        if (gr < NN) v = *(const short8*)&xagg[(size_t)gr * DD + ch * 8];
        *(short8*)&A[r * STR + ch * 8] = v;
    }
    __syncthreads();

    for (int l = 0; l < 4; ++l) {
        floatx4 acc[4][4];
        #pragma unroll
        for (int i = 0; i < 4; ++i)
            #pragma unroll
            for (int j = 0; j < 4; ++j)
                acc[i][j] = (floatx4){0.f, 0.f, 0.f, 0.f};
        const short8* W8 = (const short8*)(wf + (size_t)(2 + l) * 16384);
        #pragma unroll
        for (int kt = 0; kt < 4; ++kt) {
            short8 af[4], bfr[4];
            #pragma unroll
            for (int i = 0; i < 4; ++i)
                af[i] = *(const short8*)&A[(i * 16 + c) * STR + kt * 32 + q * 8];
            #pragma unroll
            for (int j = 0; j < 4; ++j)
                bfr[j] = W8[(kt * 8 + wn * 4 + j) * 64 + lane];
            #pragma unroll
            for (int i = 0; i < 4; ++i)
                #pragma unroll
                for (int j = 0; j < 4; ++j)
                    acc[i][j] = __builtin_amdgcn_mfma_f32_16x16x32_bf16(af[i], bfr[j], acc[i][j], 0, 0, 0);
        }

        if (l < 3) {
            const float* bb = (l == 0) ? K0b : (l == 1) ? K1b : K2b;
            float bv[4];
            #pragma unroll
            for (int j = 0; j < 4; ++j) bv[j] = bb[c + 16 * j + 64 * wn];
            float bvv[4];
            #pragma unroll
            for (int j = 0; j < 4; ++j)
                bvv[j] = (l == 0) ? bvecs[128 + c + 16 * j + 64 * wn] : 0.f;

            __syncthreads();
            #pragma unroll
            for (int i = 0; i < 4; ++i)
                #pragma unroll
                for (int r = 0; r < 4; ++r) {
                    int node = row0 + i * 16 + 4 * q + r;
                    float cn = (l == 0) ? (float)((node < NN) ? cnt[node] : 0) : 0.f;
                    float v0 = acc[i][0][r] + bv[0] + cn * bvv[0];
                    float v1 = acc[i][1][r] + bv[1] + cn * bvv[1];
                    float v2 = acc[i][2][r] + bv[2] + cn * bvv[2];
                    float v3 = acc[i][3][r] + bv[3] + cn * bvv[3];
                    if (l == 0) {
                        v0 = fast_tanh(v0); v1 = fast_tanh(v1);
                        v2 = fast_tanh(v2); v3 = fast_tanh(v3);
                    } else if (l == 1) {
                        v0 = fmaxf(v0, 0.f); v1 = fmaxf(v1, 0.f);
                        v2 = fmaxf(v2, 0.f); v3 = fmaxf(v3, 0.f);
                    }
                    ushort4 pk;
                    pk.x = f2bf(v0); pk.y = f2bf(v1); pk.z = f2bf(v2); pk.w = f2bf(v3);
                    int m = i * 16 + 4 * q + r;
                    *(ushort4*)&A[m * STR + 4 * c + 64 * wn] = pk;   // pi-packed
                }
            __syncthreads();

            if (l == 2) {
                // kb[n] = Kn[n] . U2b (Kn pi-packed in LDS; bvecs[256+] permuted)
                if (t < 64) {
                    int node = row0 + t;
                    if (node < NN) {
                        float s = 0.f;
                        #pragma unroll
                        for (int ch = 0; ch < 16; ++ch) {
                            short8 v = *(const short8*)&A[t * STR + ch * 8];
                            #pragma unroll
                            for (int e = 0; e < 8; ++e)
                                s += bf2f((unsigned short)v[e]) * bvecs[256 + ch * 8 + e];
                        }
                        kb[node] = s;
                    }
                }
            }
        } else {
            #pragma unroll
            for (int i = 0; i < 4; ++i)
                #pragma unroll
                for (int r = 0; r < 4; ++r) {
                    int node = row0 + i * 16 + 4 * q + r;
                    if (node < NN) {
                        ushort4 pk;
                        pk.x = f2bf(acc[i][0][r]);
                        pk.y = f2bf(acc[i][1][r]);
                        pk.z = f2bf(acc[i][2][r]);
                        pk.w = f2bf(acc[i][3][r]);
                        *(ushort4*)&Km[(size_t)node * DD + 4 * c + 64 * wn] = pk;
                    }
                }
        }
    }
}

// ---------------------------------------------------------------------------
// edge (single tile, src-sorted): u = tanh(q1[s]+q2[d]);
// a = relu(u@U1^T + U1b); out += a.Km[s] + kb[s]
// ---------------------------------------------------------------------------
__global__ __launch_bounds__(256) void edge_kernel(
    const unsigned short* __restrict__ q1, const unsigned short* __restrict__ q2,
    const unsigned short* __restrict__ Km, const float* __restrict__ kb,
    const int2* __restrict__ epairs,
    const unsigned short* __restrict__ wf, const float* __restrict__ U1b,
    float* __restrict__ out)
{
    __shared__ unsigned short A[128 * STR];
    __shared__ int sidx[128];
    __shared__ int didx[128];
    __shared__ float red[4];
    const int t = threadIdx.x;
    const int lane = t & 63, w = t >> 6;
    const int wm = w >> 1, wn = w & 1;
    const int c = lane & 15, q = lane >> 4;
    const int e0 = blockIdx.x * 128;

    if (t < 128) {
        int e = e0 + t;
        if (e < NE) {
            int2 p = epairs[e];
            sidx[t] = p.x;
            didx[t] = p.y;
        } else {
            sidx[t] = -1;
            didx[t] = 0;
        }
    }
    __syncthreads();

    float part = 0.f;
    if (t < 128 && sidx[t] >= 0) part += kb[sidx[t]];

    #pragma unroll
    for (int i = 0; i < 8; ++i) {
        int idx = i * 256 + t;
        int r = idx >> 4, ch = idx & 15;
        int s = sidx[r];
        int o32[4] = {0, 0, 0, 0};
        if (s >= 0) {
            short8 a8 = *(const short8*)&q1[(size_t)s * DD + ch * 8];
            short8 b8 = *(const short8*)&q2[(size_t)didx[r] * DD + ch * 8];
            #pragma unroll
            for (int k = 0; k < 8; k += 2) {
                float2 u;
                u.x = fast_tanh(bf2f((unsigned short)a8[k])     + bf2f((unsigned short)b8[k]));
                u.y = fast_tanh(bf2f((unsigned short)a8[k + 1]) + bf2f((unsigned short)b8[k + 1]));
                __hip_bfloat162 hb = __float22bfloat162_rn(u);
                __builtin_memcpy(&o32[k >> 1], &hb, 4);
            }
        }
        *(int4*)&A[r * STR + ch * 8] = *(int4*)o32;
    }
    __syncthreads();

    floatx4 acc[4][4];
    #pragma unroll
    for (int i = 0; i < 4; ++i)
        #pragma unroll
        for (int j = 0; j < 4; ++j)
            acc[i][j] = (floatx4){0.f, 0.f, 0.f, 0.f};
    const short8* W8 = (const short8*)(wf + (size_t)6 * 16384);
    #pragma unroll
    for (int kt = 0; kt < 4; ++kt) {
        short8 af[4], bfr[4];
        #pragma unroll
        for (int i = 0; i < 4; ++i)
            af[i] = *(const short8*)&A[(wm * 64 + i * 16 + c) * STR + kt * 32 + q * 8];
        #pragma unroll
        for (int j = 0; j < 4; ++j)
            bfr[j] = W8[(kt * 8 + wn * 4 + j) * 64 + lane];
        #pragma unroll
        for (int i = 0; i < 4; ++i)
            #pragma unroll
            for (int j = 0; j < 4; ++j)
                acc[i][j] = __builtin_amdgcn_mfma_f32_16x16x32_bf16(af[i], bfr[j], acc[i][j], 0, 0, 0);
    }
    float bv[4];
    #pragma unroll
    for (int j = 0; j < 4; ++j) bv[j] = U1b[c + 16 * j + 64 * wn];

    #pragma unroll
    for (int i = 0; i < 4; ++i)
        #pragma unroll
        for (int r = 0; r < 4; ++r) {
            int m = wm * 64 + i * 16 + 4 * q + r;
            int s = sidx[m];
            if (s >= 0) {
                ushort4 km4 = *(const ushort4*)&Km[(size_t)s * DD + 4 * c + 64 * wn];
                part += fmaxf(acc[i][0][r] + bv[0], 0.f) * bf2f(km4.x)
                      + fmaxf(acc[i][1][r] + bv[1], 0.f) * bf2f(km4.y)
                      + fmaxf(acc[i][2][r] + bv[2], 0.f) * bf2f(km4.z)
                      + fmaxf(acc[i][3][r] + bv[3], 0.f) * bf2f(km4.w);
            }
        }

    #pragma unroll
    for (int off = 32; off > 0; off >>= 1)
        part += __shfl_down(part, off);
    if (lane == 0) red[w] = part;
    __syncthreads();
    if (t == 0)
        atomicAdd(out, red[0] + red[1] + red[2] + red[3]);
}

// ---------------------------------------------------------------------------
extern "C" void kernel_launch(void* const* d_in, const int* in_sizes, int n_in,
                              void* d_out, int out_size, void* d_ws, size_t ws_size,
                              hipStream_t stream)
{
    const float* x     = (const float*)d_in[0];
    const int*   src   = (const int*)  d_in[1];
    const int*   dst   = (const int*)  d_in[2];
    const float* WencK = (const float*)d_in[3];
    const float* bencK = (const float*)d_in[4];
    const float* WencP1= (const float*)d_in[5];
    const float* bencP1= (const float*)d_in[6];
    const float* WencP2= (const float*)d_in[7];
    const float* bencP2= (const float*)d_in[8];
    const float* K0W   = (const float*)d_in[9];
    const float* K0b   = (const float*)d_in[10];
    const float* K1W   = (const float*)d_in[11];
    const float* K1b   = (const float*)d_in[12];
    const float* K2W   = (const float*)d_in[13];
    const float* K2b   = (const float*)d_in[14];
    const float* U0W   = (const float*)d_in[15];
    const float* U0b   = (const float*)d_in[16];
    const float* U1W   = (const float*)d_in[17];
    const float* U1b   = (const float*)d_in[18];
    const float* U2W   = (const float*)d_in[19];
    const float* U2b   = (const float*)d_in[20];

    char* ws = (char*)d_ws;
    unsigned short* wfrag = (unsigned short*)ws;             // 229 KB
    float* comp  = (float*)(ws + 0x40000);                   // 192 KB
    float* bvecs = (float*)(ws + 0x70000);                   // 1.5 KB
    unsigned short* xbf  = (unsigned short*)(ws + 0x71000);  // [N,D] bf16
    unsigned short* q1   = xbf + (size_t)NN * DD;
    unsigned short* q2   = q1 + (size_t)NN * DD;
    unsigned short* Kmg  = q2 + (size_t)NN * DD;
    unsigned short* xagg = Kmg + (size_t)NN * DD;
    float* kb       = (float*)(xagg + (size_t)NN * DD);
    int* cnt_dst    = (int*)(kb + NN);
    int* cnt_src    = cnt_dst + NN;      // contiguous with cnt_dst
    int* base       = cnt_src + NN;      // block-local scan of [cnt_dst|cnt_src]
    int* bsum       = base + NSCAN;      // SCAN_BLK block sums -> offsets
    int* rank_d     = bsum + 128;
    int* rank_s     = rank_d + NE;
    int* sorted_src_bydst = rank_s + NE;
    int2* epairs    = (int2*)(sorted_src_bydst + NE);

    hipMemsetAsync(cnt_dst, 0, 2 * NN * sizeof(int), stream);

    k1_kernel<<<HIST_BLK + CVT_BLK + 7, 256, 0, stream>>>(
        src, dst, cnt_dst, cnt_src, rank_d, rank_s, x, xbf,
        U0W, WencP1, WencP2, K0W, WencK, bencP1, bencP2, U0b, bencK, U2b,
        comp, bvecs);

    k2_kernel<<<PRECONV_BLK + SCAN_BLK, 1024, 0, stream>>>(
        comp, K1W, K2W, U2W, U1W, wfrag, cnt_dst, base, bsum);

    scan2_kernel<<<1, 128, 0, stream>>>(bsum, (float*)d_out);

    place_kernel<<<HIST_BLK, 256, 0, stream>>>(
        src, dst, base, bsum, rank_d, rank_s, sorted_src_bydst, epairs);

    aggenc_kernel<<<ENC_BLK + AGG_BLK, 256, 0, stream>>>(
        x, xbf, wfrag, bvecs, base, bsum, cnt_dst, sorted_src_bydst,
        q1, q2, xagg);

    node_kernel<<<NODE_BLK, 128, 0, stream>>>(
        xagg, wfrag, cnt_dst, bvecs, K0b, K1b, K2b, Kmg, kb);

    edge_kernel<<<(NE + 127) / 128, 256, 0, stream>>>(
        q1, q2, Kmg, kb, epairs, wfrag, U1b, (float*)d_out);
}

// Round 10
// 327.345 us; speedup vs baseline: 1.1532x; 1.1532x over previous
//
#include <hip/hip_runtime.h>
#include <hip/hip_bf16.h>
#include <math.h>

#define NN 50000
#define NE 500000
#define DD 128
#define STR 136   // LDS activation row stride in bf16 elements
#define NSCAN (2 * NN)
#define SCAN_BLK ((NSCAN + 1023) / 1024)          // 98
#define HIST_BLK ((NE + 255) / 256)               // 1954
#define CVT_BLK  ((NN * DD + 4095) / 4096)        // 1563
#define PRECONV_BLK ((7 * 2048 + 1023) / 1024)    // 14
#define ENC_BLK  ((NN + 127) / 128)               // 391

typedef __attribute__((ext_vector_type(8))) short short8;
typedef __attribute__((ext_vector_type(4))) float floatx4;

__device__ __forceinline__ float bf2f(unsigned short u) {
    unsigned v = ((unsigned)u) << 16;
    float f;
    __builtin_memcpy(&f, &v, 4);
    return f;
}
__device__ __forceinline__ unsigned short f2bf(float f) {
    unsigned x;
    __builtin_memcpy(&x, &f, 4);
    x += 0x7FFF + ((x >> 16) & 1);   // RNE
    return (unsigned short)(x >> 16);
}
// tanh(x) = 1 - 2/(e^{2x}+1). Branch-free, 2 transcendentals.
__device__ __forceinline__ float fast_tanh(float x) {
    float t = __builtin_amdgcn_exp2f(x * 2.88539008177793f);
    return 1.f - 2.f * __builtin_amdgcn_rcpf(t + 1.f);
}

// ---------------------------------------------------------------------------
// K1: three independent jobs in one dispatch.
//  blocks [0,1954):         hist (dual counting-sort histograms + ranks)
//  blocks [1954,1954+1563): x (f32) -> xbf (bf16), coalesced
//  blocks [3517,3517+7):    composite weights + bias vectors
// ---------------------------------------------------------------------------
__global__ __launch_bounds__(256) void k1_kernel(
    const int* __restrict__ src, const int* __restrict__ dst,
    int* __restrict__ cnt_dst, int* __restrict__ cnt_src,
    int* __restrict__ rank_d, int* __restrict__ rank_s,
    const float* __restrict__ x, unsigned short* __restrict__ xbf,
    const float* __restrict__ U0W, const float* __restrict__ WencP1,
    const float* __restrict__ WencP2, const float* __restrict__ K0W,
    const float* __restrict__ WencK,
    const float* __restrict__ bp1, const float* __restrict__ bp2,
    const float* __restrict__ U0b, const float* __restrict__ bk,
    const float* __restrict__ U2b,
    float* __restrict__ comp, float* __restrict__ bvecs)
{
    __shared__ float Bs[DD * DD];
    int blk = blockIdx.x;
    int t = threadIdx.x;

    if (blk < HIST_BLK) {
        int e = blk * 256 + t;
        if (e < NE) {
            rank_d[e] = atomicAdd(&cnt_dst[dst[e]], 1);
            rank_s[e] = atomicAdd(&cnt_src[src[e]], 1);
        }
        return;
    }
    if (blk < HIST_BLK + CVT_BLK) {
        int base = (blk - HIST_BLK) * 4096;
        #pragma unroll
        for (int j = 0; j < 4; ++j) {
            int idx = base + (j * 256 + t) * 4;
            if (idx < NN * DD) {
                float4 f = *(const float4*)&x[idx];
                ushort4 v4;
                v4.x = f2bf(f.x); v4.y = f2bf(f.y);
                v4.z = f2bf(f.z); v4.w = f2bf(f.w);
                *(ushort4*)&xbf[idx] = v4;
            }
        }
        return;
    }

    int b = blk - (HIST_BLK + CVT_BLK);   // 0..6
    if (b == 6) {
        if (t < 128) {
            float s1 = 0.f, s2 = 0.f;
            for (int k = 0; k < DD; ++k) {
                s1 += U0W[t * DD + k] * (bp1[k] + bp2[k]);
                s2 += K0W[t * DD + k] * bk[k];
            }
            bvecs[t] = s1 + U0b[t];
            bvecs[128 + t] = s2;
            int f = (t & 64) + 16 * (t & 3) + ((t & 63) >> 2);
            bvecs[256 + t] = U2b[f];
        }
        return;
    }
    int mat = b >> 1, half = b & 1;
    const float* A = (mat == 2) ? K0W : U0W;
    const float* B = (mat == 0) ? WencP1 : (mat == 1) ? WencP2 : WencK;
    float* C = comp + (size_t)mat * DD * DD;
    for (int i = 0; i < 64; ++i)
        Bs[i * 256 + t] = B[i * 256 + t];
    __syncthreads();
    int row = half * 64 + (t >> 2);
    int j0 = (t & 3) * 32;
    float acc[32];
    #pragma unroll
    for (int jj = 0; jj < 32; ++jj) acc[jj] = 0.f;
    for (int k = 0; k < DD; ++k) {
        float a = A[row * DD + k];
        #pragma unroll
        for (int jj = 0; jj < 32; ++jj)
            acc[jj] += a * Bs[k * DD + j0 + jj];
    }
    #pragma unroll
    for (int jj = 0; jj < 32; ++jj) C[row * DD + j0 + jj] = acc[jj];
}

// ---------------------------------------------------------------------------
// K2: preconv (frag conversion) blocks [0,14) + scan1 blocks [14,112).
// scan1 leaves block-LOCAL exclusive prefixes in base; bsum gets block sums.
// ---------------------------------------------------------------------------
__global__ __launch_bounds__(1024) void k2_kernel(
    const float* __restrict__ comp, const float* __restrict__ K1W,
    const float* __restrict__ K2W, const float* __restrict__ U2W,
    const float* __restrict__ U1W, unsigned short* __restrict__ wfrag,
    const int* __restrict__ cnt, int* __restrict__ base, int* __restrict__ bsum)
{
    int t = threadIdx.x;
    if (blockIdx.x < PRECONV_BLK) {
        int g = blockIdx.x * 1024 + t;
        if (g >= 7 * 2048) return;
        int m = g >> 11;
        int rem = g & 2047;
        int kt = rem >> 9, nt = (rem >> 6) & 7, lane = rem & 63;
        const float* W;
        bool perm = false, tr = false;
        switch (m) {
            case 0: W = comp; break;
            case 1: W = comp + 16384; break;
            case 2: W = comp + 32768; break;
            case 3: W = K1W; perm = true; break;
            case 4: W = K2W; perm = true; break;
            case 5: W = U2W; perm = true; tr = true; break;
            default: W = U1W; break;
        }
        int n = nt * 16 + (lane & 15);
        #pragma unroll
        for (int j = 0; j < 8; ++j) {
            int ks = kt * 32 + (lane >> 4) * 8 + j;
            int f = perm ? (ks & 64) + 16 * (ks & 3) + ((ks & 63) >> 2) : ks;
            float v = tr ? W[f * DD + n] : W[n * DD + f];
            wfrag[(size_t)g * 8 + j] = f2bf(v);
        }
        return;
    }
    // scan1 over concatenated [cnt_dst | cnt_src]
    __shared__ int wsum[16];
    int sb = blockIdx.x - PRECONV_BLK;
    int i = sb * 1024 + t;
    int v = (i < NSCAN) ? cnt[i] : 0;
    int lane = t & 63, w = t >> 6;
    int xv = v;
    #pragma unroll
    for (int off = 1; off < 64; off <<= 1) {
        int y = __shfl_up(xv, off);
        if (lane >= off) xv += y;
    }
    if (lane == 63) wsum[w] = xv;
    __syncthreads();
    if (w == 0) {
        int s = (lane < 16) ? wsum[lane] : 0;
        #pragma unroll
        for (int off = 1; off < 16; off <<= 1) {
            int y = __shfl_up(s, off);
            if (lane >= off) s += y;
        }
        if (lane < 16) wsum[lane] = s;
    }
    __syncthreads();
    int wavebase = (w == 0) ? 0 : wsum[w - 1];
    int incl = wavebase + xv;
    if (i < NSCAN) base[i] = incl - v;
    if (t == 1023) bsum[sb] = incl;
}

__global__ __launch_bounds__(128) void scan2_kernel(
    int* __restrict__ bsum, float* __restrict__ out)
{
    if (threadIdx.x == 0 && blockIdx.x == 0) *out = 0.f;  // zero d_out here
    __shared__ int wsum[2];
    int t = threadIdx.x;
    int v = (t < SCAN_BLK) ? bsum[t] : 0;
    int lane = t & 63, w = t >> 6;
    int x = v;
    #pragma unroll
    for (int off = 1; off < 64; off <<= 1) {
        int y = __shfl_up(x, off);
        if (lane >= off) x += y;
    }
    if (lane == 63) wsum[w] = x;
    __syncthreads();
    int wavebase = (w == 0) ? 0 : wsum[0];
    int incl = wavebase + x;
    if (t < SCAN_BLK) bsum[t] = incl - v;
}

// ---------------------------------------------------------------------------
// place: global offset = base[i] (block-local) + bsum[i>>10] (block offset).
// by-src output packed as int2 (sid, dst) -> one 8B scatter.
// ---------------------------------------------------------------------------
__global__ __launch_bounds__(256) void place_kernel(
    const int* __restrict__ src, const int* __restrict__ dst,
    const int* __restrict__ base, const int* __restrict__ bsum,
    const int* __restrict__ rank_d, const int* __restrict__ rank_s,
    int* __restrict__ sorted_src_bydst, int2* __restrict__ epairs)
{
    int e = blockIdx.x * 256 + threadIdx.x;
    if (e < NE) {
        int s = src[e], d = dst[e];
        sorted_src_bydst[base[d] + bsum[d >> 10] + rank_d[e]] = s;
        int si = NN + s;
        int p = base[si] + bsum[si >> 10] + rank_s[e] - NE;
        epairs[p] = make_int2(s, d);
    }
}

// ---------------------------------------------------------------------------
// agg (standalone, small VGPR footprint -> high occupancy): one wave/node,
// 4-way unrolled gather for memory-level parallelism.
// ---------------------------------------------------------------------------
__global__ __launch_bounds__(256) void agg_kernel(
    const unsigned short* __restrict__ xbf,
    const int* __restrict__ base, const int* __restrict__ bsum,
    const int* __restrict__ cnt, const int* __restrict__ sorted_src,
    unsigned short* __restrict__ xagg)
{
    int node = blockIdx.x * 4 + (threadIdx.x >> 6);
    int lane = threadIdx.x & 63;
    if (node >= NN) return;
    int lo = base[node] + bsum[node >> 10];
    int hi = lo + cnt[node];
    float ax = 0.f, ay = 0.f;
    for (int off = lo; off < hi; off += 64) {
        int myid = (off + lane < hi) ? sorted_src[off + lane] : 0;
        int nk = min(64, hi - off);
        int k = 0;
        for (; k + 4 <= nk; k += 4) {
            int s0 = __shfl(myid, k);
            int s1 = __shfl(myid, k + 1);
            int s2 = __shfl(myid, k + 2);
            int s3 = __shfl(myid, k + 3);
            ushort2 v0 = *(const ushort2*)&xbf[(size_t)s0 * DD + lane * 2];
            ushort2 v1 = *(const ushort2*)&xbf[(size_t)s1 * DD + lane * 2];
            ushort2 v2 = *(const ushort2*)&xbf[(size_t)s2 * DD + lane * 2];
            ushort2 v3 = *(const ushort2*)&xbf[(size_t)s3 * DD + lane * 2];
            ax += bf2f(v0.x) + bf2f(v1.x) + bf2f(v2.x) + bf2f(v3.x);
            ay += bf2f(v0.y) + bf2f(v1.y) + bf2f(v2.y) + bf2f(v3.y);
        }
        for (; k < nk; ++k) {
            int s = __shfl(myid, k);
            ushort2 v = *(const ushort2*)&xbf[(size_t)s * DD + lane * 2];
            ax += bf2f(v.x);
            ay += bf2f(v.y);
        }
    }
    ushort2 o;
    o.x = f2bf(ax); o.y = f2bf(ay);
    *(ushort2*)&xagg[(size_t)node * DD + lane * 2] = o;
}

// ---------------------------------------------------------------------------
// encnode: blocks [0,391) = enc (q1,q2 from x); blocks [391,782) = node
// (4-GEMM chain on xagg -> Km, kb). Independent jobs, one dispatch.
// ---------------------------------------------------------------------------
__global__ __launch_bounds__(256) void encnode_kernel(
    const float* __restrict__ x, const unsigned short* __restrict__ xagg,
    const unsigned short* __restrict__ wf, const float* __restrict__ bvecs,
    const int* __restrict__ cnt,
    const float* __restrict__ K0b, const float* __restrict__ K1b,
    const float* __restrict__ K2b,
    unsigned short* __restrict__ q1, unsigned short* __restrict__ q2,
    unsigned short* __restrict__ Km, float* __restrict__ kb)
{
    __shared__ unsigned short A[128 * STR];
    const int t = threadIdx.x;
    const int lane = t & 63, w = t >> 6;
    const int wm = w >> 1, wn = w & 1;
    const int c = lane & 15, q = lane >> 4;

    if (blockIdx.x < ENC_BLK) {
        // ---------------- enc ----------------
        const int row0 = blockIdx.x * 128;
        #pragma unroll
        for (int i = 0; i < 16; ++i) {
            int idx = i * 256 + t;
            int r = idx >> 5, ch = idx & 31;
            int gr = row0 + r;
            ushort4 v4 = {0, 0, 0, 0};
            if (gr < NN) {
                float4 f = *(const float4*)&x[(size_t)gr * DD + ch * 4];
                v4.x = f2bf(f.x); v4.y = f2bf(f.y);
                v4.z = f2bf(f.z); v4.w = f2bf(f.w);
            }
            *(ushort4*)&A[r * STR + ch * 4] = v4;
        }
        __syncthreads();

        for (int l = 0; l < 2; ++l) {
            floatx4 acc[4][4];
            #pragma unroll
            for (int i = 0; i < 4; ++i)
                #pragma unroll
                for (int j = 0; j < 4; ++j)
                    acc[i][j] = (floatx4){0.f, 0.f, 0.f, 0.f};
            const short8* W8 = (const short8*)(wf + (size_t)l * 16384);
            #pragma unroll
            for (int kt = 0; kt < 4; ++kt) {
                short8 af[4], bfr[4];
                #pragma unroll
                for (int i = 0; i < 4; ++i)
                    af[i] = *(const short8*)&A[(wm * 64 + i * 16 + c) * STR + kt * 32 + q * 8];
                #pragma unroll
                for (int j = 0; j < 4; ++j)
                    bfr[j] = W8[(kt * 8 + wn * 4 + j) * 64 + lane];
                #pragma unroll
                for (int i = 0; i < 4; ++i)
                    #pragma unroll
                    for (int j = 0; j < 4; ++j)
                        acc[i][j] = __builtin_amdgcn_mfma_f32_16x16x32_bf16(af[i], bfr[j], acc[i][j], 0, 0, 0);
            }
            unsigned short* pp = (l == 0) ? q1 : q2;
            float bv[4];
            #pragma unroll
            for (int j = 0; j < 4; ++j)
                bv[j] = (l == 0) ? bvecs[c + 16 * j + 64 * wn] : 0.f;

            #pragma unroll
            for (int i = 0; i < 4; ++i)
                #pragma unroll
                for (int r = 0; r < 4; ++r) {
                    int node = row0 + wm * 64 + i * 16 + 4 * q + r;
                    if (node < NN) {
                        #pragma unroll
                        for (int j = 0; j < 4; ++j)
                            pp[(size_t)node * DD + c + 16 * j + 64 * wn] = f2bf(acc[i][j][r] + bv[j]);
                    }
                }
        }
        return;
    }

    // ---------------- node ----------------
    const int row0 = (blockIdx.x - ENC_BLK) * 128;
    #pragma unroll
    for (int i = 0; i < 8; ++i) {
        int idx = i * 256 + t;
        int r = idx >> 4, ch = idx & 15;
        int gr = row0 + r;
        short8 v = (short8){0,0,0,0,0,0,0,0};
        if (gr < NN) v = *(const short8*)&xagg[(size_t)gr * DD + ch * 8];
        *(short8*)&A[r * STR + ch * 8] = v;
    }
    __syncthreads();

    for (int l = 0; l < 4; ++l) {
        floatx4 acc[4][4];
        #pragma unroll
        for (int i = 0; i < 4; ++i)
            #pragma unroll
            for (int j = 0; j < 4; ++j)
                acc[i][j] = (floatx4){0.f, 0.f, 0.f, 0.f};
        const short8* W8 = (const short8*)(wf + (size_t)(2 + l) * 16384);
        #pragma unroll
        for (int kt = 0; kt < 4; ++kt) {
            short8 af[4], bfr[4];
            #pragma unroll
            for (int i = 0; i < 4; ++i)
                af[i] = *(const short8*)&A[(wm * 64 + i * 16 + c) * STR + kt * 32 + q * 8];
            #pragma unroll
            for (int j = 0; j < 4; ++j)
                bfr[j] = W8[(kt * 8 + wn * 4 + j) * 64 + lane];
            #pragma unroll
            for (int i = 0; i < 4; ++i)
                #pragma unroll
                for (int j = 0; j < 4; ++j)
                    acc[i][j] = __builtin_amdgcn_mfma_f32_16x16x32_bf16(af[i], bfr[j], acc[i][j], 0, 0, 0);
        }

        if (l < 3) {
            const float* bb = (l == 0) ? K0b : (l == 1) ? K1b : K2b;
            float bv[4];
            #pragma unroll
            for (int j = 0; j < 4; ++j) bv[j] = bb[c + 16 * j + 64 * wn];
            float bvv[4];
            #pragma unroll
            for (int j = 0; j < 4; ++j)
                bvv[j] = (l == 0) ? bvecs[128 + c + 16 * j + 64 * wn] : 0.f;

            __syncthreads();
            #pragma unroll
            for (int i = 0; i < 4; ++i)
                #pragma unroll
                for (int r = 0; r < 4; ++r) {
                    int node = row0 + wm * 64 + i * 16 + 4 * q + r;
                    float cn = (l == 0) ? (float)((node < NN) ? cnt[node] : 0) : 0.f;
                    float v0 = acc[i][0][r] + bv[0] + cn * bvv[0];
                    float v1 = acc[i][1][r] + bv[1] + cn * bvv[1];
                    float v2 = acc[i][2][r] + bv[2] + cn * bvv[2];
                    float v3 = acc[i][3][r] + bv[3] + cn * bvv[3];
                    if (l == 0) {
                        v0 = fast_tanh(v0); v1 = fast_tanh(v1);
                        v2 = fast_tanh(v2); v3 = fast_tanh(v3);
                    } else if (l == 1) {
                        v0 = fmaxf(v0, 0.f); v1 = fmaxf(v1, 0.f);
                        v2 = fmaxf(v2, 0.f); v3 = fmaxf(v3, 0.f);
                    }
                    ushort4 pk;
                    pk.x = f2bf(v0); pk.y = f2bf(v1); pk.z = f2bf(v2); pk.w = f2bf(v3);
                    int m = wm * 64 + i * 16 + 4 * q + r;
                    *(ushort4*)&A[m * STR + 4 * c + 64 * wn] = pk;   // pi-packed
                }
            __syncthreads();

            if (l == 2) {
                // kb[n] = Kn[n] . U2b (Kn pi-packed in LDS; bvecs[256+] permuted)
                if (t < 128) {
                    int node = row0 + t;
                    if (node < NN) {
                        float s = 0.f;
                        #pragma unroll
                        for (int ch = 0; ch < 16; ++ch) {
                            short8 v = *(const short8*)&A[t * STR + ch * 8];
                            #pragma unroll
                            for (int e = 0; e < 8; ++e)
                                s += bf2f((unsigned short)v[e]) * bvecs[256 + ch * 8 + e];
                        }
                        kb[node] = s;
                    }
                }
            }
        } else {
            #pragma unroll
            for (int i = 0; i < 4; ++i)
                #pragma unroll
                for (int r = 0; r < 4; ++r) {
                    int node = row0 + wm * 64 + i * 16 + 4 * q + r;
                    if (node < NN) {
                        ushort4 pk;
                        pk.x = f2bf(acc[i][0][r]);
                        pk.y = f2bf(acc[i][1][r]);
                        pk.z = f2bf(acc[i][2][r]);
                        pk.w = f2bf(acc[i][3][r]);
                        *(ushort4*)&Km[(size_t)node * DD + 4 * c + 64 * wn] = pk;
                    }
                }
        }
    }
}

// ---------------------------------------------------------------------------
// edge (single tile, src-sorted): u = tanh(q1[s]+q2[d]);
// a = relu(u@U1^T + U1b); out += a.Km[s] + kb[s]
// ---------------------------------------------------------------------------
__global__ __launch_bounds__(256) void edge_kernel(
    const unsigned short* __restrict__ q1, const unsigned short* __restrict__ q2,
    const unsigned short* __restrict__ Km, const float* __restrict__ kb,
    const int2* __restrict__ epairs,
    const unsigned short* __restrict__ wf, const float* __restrict__ U1b,
    float* __restrict__ out)
{
    __shared__ unsigned short A[128 * STR];
    __shared__ int sidx[128];
    __shared__ int didx[128];
    __shared__ float red[4];
    const int t = threadIdx.x;
    const int lane = t & 63, w = t >> 6;
    const int wm = w >> 1, wn = w & 1;
    const int c = lane & 15, q = lane >> 4;
    const int e0 = blockIdx.x * 128;

    if (t < 128) {
        int e = e0 + t;
        if (e < NE) {
            int2 p = epairs[e];
            sidx[t] = p.x;
            didx[t] = p.y;
        } else {
            sidx[t] = -1;
            didx[t] = 0;
        }
    }
    __syncthreads();

    float part = 0.f;
    if (t < 128 && sidx[t] >= 0) part += kb[sidx[t]];

    #pragma unroll
    for (int i = 0; i < 8; ++i) {
        int idx = i * 256 + t;
        int r = idx >> 4, ch = idx & 15;
        int s = sidx[r];
        int o32[4] = {0, 0, 0, 0};
        if (s >= 0) {
            short8 a8 = *(const short8*)&q1[(size_t)s * DD + ch * 8];
            short8 b8 = *(const short8*)&q2[(size_t)didx[r] * DD + ch * 8];
            #pragma unroll
            for (int k = 0; k < 8; k += 2) {
                float2 u;
                u.x = fast_tanh(bf2f((unsigned short)a8[k])     + bf2f((unsigned short)b8[k]));
                u.y = fast_tanh(bf2f((unsigned short)a8[k + 1]) + bf2f((unsigned short)b8[k + 1]));
                __hip_bfloat162 hb = __float22bfloat162_rn(u);
                __builtin_memcpy(&o32[k >> 1], &hb, 4);
            }
        }
        *(int4*)&A[r * STR + ch * 8] = *(int4*)o32;
    }
    __syncthreads();

    floatx4 acc[4][4];
    #pragma unroll
    for (int i = 0; i < 4; ++i)
        #pragma unroll
        for (int j = 0; j < 4; ++j)
            acc[i][j] = (floatx4){0.f, 0.f, 0.f, 0.f};
    const short8* W8 = (const short8*)(wf + (size_t)6 * 16384);
    #pragma unroll
    for (int kt = 0; kt < 4; ++kt) {
        short8 af[4], bfr[4];
        #pragma unroll
        for (int i = 0; i < 4; ++i)
            af[i] = *(const short8*)&A[(wm * 64 + i * 16 + c) * STR + kt * 32 + q * 8];
        #pragma unroll
        for (int j = 0; j < 4; ++j)
            bfr[j] = W8[(kt * 8 + wn * 4 + j) * 64 + lane];
        #pragma unroll
        for (int i = 0; i < 4; ++i)
            #pragma unroll
            for (int j = 0; j < 4; ++j)
                acc[i][j] = __builtin_amdgcn_mfma_f32_16x16x32_bf16(af[i], bfr[j], acc[i][j], 0, 0, 0);
    }
    float bv[4];
    #pragma unroll
    for (int j = 0; j < 4; ++j) bv[j] = U1b[c + 16 * j + 64 * wn];

    #pragma unroll
    for (int i = 0; i < 4; ++i)
        #pragma unroll
        for (int r = 0; r < 4; ++r) {
            int m = wm * 64 + i * 16 + 4 * q + r;
            int s = sidx[m];
            if (s >= 0) {
                ushort4 km4 = *(const ushort4*)&Km[(size_t)s * DD + 4 * c + 64 * wn];
                part += fmaxf(acc[i][0][r] + bv[0], 0.f) * bf2f(km4.x)
                      + fmaxf(acc[i][1][r] + bv[1], 0.f) * bf2f(km4.y)
                      + fmaxf(acc[i][2][r] + bv[2], 0.f) * bf2f(km4.z)
                      + fmaxf(acc[i][3][r] + bv[3], 0.f) * bf2f(km4.w);
            }
        }

    #pragma unroll
    for (int off = 32; off > 0; off >>= 1)
        part += __shfl_down(part, off);
    if (lane == 0) red[w] = part;
    __syncthreads();
    if (t == 0)
        atomicAdd(out, red[0] + red[1] + red[2] + red[3]);
}

// ---------------------------------------------------------------------------
extern "C" void kernel_launch(void* const* d_in, const int* in_sizes, int n_in,
                              void* d_out, int out_size, void* d_ws, size_t ws_size,
                              hipStream_t stream)
{
    const float* x     = (const float*)d_in[0];
    const int*   src   = (const int*)  d_in[1];
    const int*   dst   = (const int*)  d_in[2];
    const float* WencK = (const float*)d_in[3];
    const float* bencK = (const float*)d_in[4];
    const float* WencP1= (const float*)d_in[5];
    const float* bencP1= (const float*)d_in[6];
    const float* WencP2= (const float*)d_in[7];
    const float* bencP2= (const float*)d_in[8];
    const float* K0W   = (const float*)d_in[9];
    const float* K0b   = (const float*)d_in[10];
    const float* K1W   = (const float*)d_in[11];
    const float* K1b   = (const float*)d_in[12];
    const float* K2W   = (const float*)d_in[13];
    const float* K2b   = (const float*)d_in[14];
    const float* U0W   = (const float*)d_in[15];
    const float* U0b   = (const float*)d_in[16];
    const float* U1W   = (const float*)d_in[17];
    const float* U1b   = (const float*)d_in[18];
    const float* U2W   = (const float*)d_in[19];
    const float* U2b   = (const float*)d_in[20];

    char* ws = (char*)d_ws;
    unsigned short* wfrag = (unsigned short*)ws;             // 229 KB
    float* comp  = (float*)(ws + 0x40000);                   // 192 KB
    float* bvecs = (float*)(ws + 0x70000);                   // 1.5 KB
    unsigned short* xbf  = (unsigned short*)(ws + 0x71000);  // [N,D] bf16
    unsigned short* q1   = xbf + (size_t)NN * DD;
    unsigned short* q2   = q1 + (size_t)NN * DD;
    unsigned short* Kmg  = q2 + (size_t)NN * DD;
    unsigned short* xagg = Kmg + (size_t)NN * DD;
    float* kb       = (float*)(xagg + (size_t)NN * DD);
    int* cnt_dst    = (int*)(kb + NN);
    int* cnt_src    = cnt_dst + NN;      // contiguous with cnt_dst
    int* base       = cnt_src + NN;      // block-local scan of [cnt_dst|cnt_src]
    int* bsum       = base + NSCAN;      // SCAN_BLK block sums -> offsets
    int* rank_d     = bsum + 128;
    int* rank_s     = rank_d + NE;
    int* sorted_src_bydst = rank_s + NE;
    int2* epairs    = (int2*)(sorted_src_bydst + NE);

    hipMemsetAsync(cnt_dst, 0, 2 * NN * sizeof(int), stream);

    k1_kernel<<<HIST_BLK + CVT_BLK + 7, 256, 0, stream>>>(
        src, dst, cnt_dst, cnt_src, rank_d, rank_s, x, xbf,
        U0W, WencP1, WencP2, K0W, WencK, bencP1, bencP2, U0b, bencK, U2b,
        comp, bvecs);

    k2_kernel<<<PRECONV_BLK + SCAN_BLK, 1024, 0, stream>>>(
        comp, K1W, K2W, U2W, U1W, wfrag, cnt_dst, base, bsum);

    scan2_kernel<<<1, 128, 0, stream>>>(bsum, (float*)d_out);

    place_kernel<<<HIST_BLK, 256, 0, stream>>>(
        src, dst, base, bsum, rank_d, rank_s, sorted_src_bydst, epairs);

    agg_kernel<<<(NN + 3) / 4, 256, 0, stream>>>(
        xbf, base, bsum, cnt_dst, sorted_src_bydst, xagg);

    encnode_kernel<<<2 * ENC_BLK, 256, 0, stream>>>(
        x, xagg, wfrag, bvecs, cnt_dst, K0b, K1b, K2b, q1, q2, Kmg, kb);

    edge_kernel<<<(NE + 127) / 128, 256, 0, stream>>>(
        q1, q2, Kmg, kb, epairs, wfrag, U1b, (float*)d_out);
}